// Round 10
// baseline (579.542 us; speedup 1.0000x reference)
//
#include <hip/hip_runtime.h>

// Langevin dynamics, bit-matched to JAX Threefry-2x32 *partitionable* RNG:
//   split(key, n):  keys[t] = threefry2x32(key=(0,1), counter=(0, t))
//   random_bits32:  bits[i] = o0 ^ o1 of threefry2x32(key_t, counter=(0, i))
// R10 = R9 with inline-asm operand numbering fixed (%2 = pointer; outputs
// early-clobbered). Wave-uniform step keys live in SGPRs via s_load_dwordx4
// from a d_ws key table (written by keygen kernel), software-pipelined two
// quads ahead; threefry key injections read SGPRs directly (1 SGPR/VALU op
// is legal), no LDS, no barriers, no key unpack movs.

typedef unsigned v4u __attribute__((ext_vector_type(4)));

__device__ __forceinline__ float sconst(float v) {
  return __uint_as_float(__builtin_amdgcn_readfirstlane(__float_as_uint(v)));
}

__device__ __forceinline__ void tf2x32(unsigned k0, unsigned k1,
                                       unsigned c0, unsigned c1,
                                       unsigned& o0, unsigned& o1) {
  const unsigned k2 = k0 ^ k1 ^ 0x1BD11BDAu;
  unsigned x0 = c0 + k0, x1 = c1 + k1;
#define TF1(R) x0 += x1; x1 = ((x1 << (R)) | (x1 >> (32 - (R)))); x1 ^= x0;
  TF1(13) TF1(15) TF1(26) TF1(6)  x0 += k1; x1 += k2 + 1u;
  TF1(17) TF1(29) TF1(16) TF1(24) x0 += k2; x1 += k0 + 2u;
  TF1(13) TF1(15) TF1(26) TF1(6)  x0 += k0; x1 += k1 + 3u;
  TF1(17) TF1(29) TF1(16) TF1(24) x0 += k1; x1 += k2 + 4u;
  TF1(13) TF1(15) TF1(26) TF1(6)  x0 += k2; x1 += k0 + 5u;
#undef TF1
  o0 = x0; o1 = x1;
}

// Two statement-interleaved threefry chains; keys are wave-uniform (SGPR)
// quads {k0,k1,k2,pad}. Counter (0, cj). Injections shaped for v_add3.
__device__ __forceinline__ void tf_fold2k(v4u ka, v4u kb, unsigned cj,
                                          unsigned& ra, unsigned& rb) {
  unsigned a0 = ka[0], a1 = cj + ka[1];
  unsigned b0 = kb[0], b1 = cj + kb[1];
#define TFR2(R)                                   \
  a0 += a1; b0 += b1;                             \
  a1 = ((a1 << (R)) | (a1 >> (32 - (R)))) ^ a0;   \
  b1 = ((b1 << (R)) | (b1 >> (32 - (R)))) ^ b0;
  TFR2(13) TFR2(15) TFR2(26) TFR2(6)
  a0 += ka[1]; b0 += kb[1]; a1 = a1 + ka[2] + 1u; b1 = b1 + kb[2] + 1u;
  TFR2(17) TFR2(29) TFR2(16) TFR2(24)
  a0 += ka[2]; b0 += kb[2]; a1 = a1 + ka[0] + 2u; b1 = b1 + kb[0] + 2u;
  TFR2(13) TFR2(15) TFR2(26) TFR2(6)
  a0 += ka[0]; b0 += kb[0]; a1 = a1 + ka[1] + 3u; b1 = b1 + kb[1] + 3u;
  TFR2(17) TFR2(29) TFR2(16) TFR2(24)
  a0 += ka[1]; b0 += kb[1]; a1 = a1 + ka[2] + 4u; b1 = b1 + kb[2] + 4u;
  TFR2(13) TFR2(15) TFR2(26) TFR2(6)
  a0 += ka[2]; b0 += kb[2]; a1 = a1 + ka[0] + 5u; b1 = b1 + kb[0] + 5u;
#undef TFR2
  ra = a0 ^ a1;
  rb = b0 ^ b1;
}

// ---- kernel 1: key table -> d_ws (512 entries of {k0,k1,k2,pad}) ----
__global__ void keygen(uint4* __restrict__ kw) {
  const int l = (int)(blockIdx.x * blockDim.x + threadIdx.x);
  if (l < 512) {
    unsigned o0, o1;
    tf2x32(0u, 1u, 0u, (unsigned)l, o0, o1);
    kw[l] = make_uint4(o0, o1, o0 ^ o1 ^ 0x1BD11BDAu, 0u);
  }
}

// two normals + two folded Langevin updates (R8's proven body)
#define NORM2_UPDATE(ra, rb)                                                 \
  {                                                                          \
    const float fa = __uint_as_float(((ra) >> 9) | 0x3F800000u) - 1.0f;      \
    const float fb = __uint_as_float(((rb) >> 9) | 0x3F800000u) - 1.0f;      \
    const float ua = fmaf(fa, 2.0f, LO);                                     \
    const float ub = fmaf(fb, 2.0f, LO);                                     \
    const float wa = __log2f(1.0f - ua * ua) * NLN2;                         \
    const float wb = __log2f(1.0f - ub * ub) * NLN2;                         \
    const float za = wa - 2.5f;                                              \
    const float zb = wb - 2.5f;                                              \
    float pa = C8, pb = C8;                                                  \
    pa = fmaf(pa, za, C7); pb = fmaf(pb, zb, C7);                            \
    pa = fmaf(pa, za, C6); pb = fmaf(pb, zb, C6);                            \
    pa = fmaf(pa, za, C5); pb = fmaf(pb, zb, C5);                            \
    pa = fmaf(pa, za, C4); pb = fmaf(pb, zb, C4);                            \
    pa = fmaf(pa, za, C3); pb = fmaf(pb, zb, C3);                            \
    pa = fmaf(pa, za, C2); pb = fmaf(pb, zb, C2);                            \
    pa = fmaf(pa, za, C1); pb = fmaf(pb, zb, C1);                            \
    pa = fmaf(pa, za, C0); pb = fmaf(pb, zb, C0);                            \
    float ea = pa * ua;                                                      \
    float eb = pb * ub;                                                      \
    if (__any((wa >= 5.0f) | (wb >= 5.0f))) {  /* rare tail */               \
      const float qza = __builtin_amdgcn_sqrtf(wa) - 3.0f;                   \
      const float qzb = __builtin_amdgcn_sqrtf(wb) - 3.0f;                   \
      float qa = T8, qb = T8;                                                \
      qa = fmaf(qa, qza, T7); qb = fmaf(qb, qzb, T7);                        \
      qa = fmaf(qa, qza, T6); qb = fmaf(qb, qzb, T6);                        \
      qa = fmaf(qa, qza, T5); qb = fmaf(qb, qzb, T5);                        \
      qa = fmaf(qa, qza, T4); qb = fmaf(qb, qzb, T4);                        \
      qa = fmaf(qa, qza, T3); qb = fmaf(qb, qzb, T3);                        \
      qa = fmaf(qa, qza, T2); qb = fmaf(qb, qzb, T2);                        \
      qa = fmaf(qa, qza, T1); qb = fmaf(qb, qzb, T1);                        \
      qa = fmaf(qa, qza, T0); qb = fmaf(qb, qzb, T0);                        \
      ea = (wa >= 5.0f) ? qa * ua : ea;                                      \
      eb = (wb >= 5.0f) ? qb * ub : eb;                                      \
    }                                                                        \
    float x3 = (x * x) * x;                                                  \
    x = fmaf(x, A1, fmaf(x3, A3, fmaf(ea, CS, bp)));                         \
    x3 = (x * x) * x;                                                        \
    x = fmaf(x, A1, fmaf(x3, A3, fmaf(eb, CS, bp)));                         \
  }

#define DECL_CONSTS                                                          \
  const float LO = sconst(-0.99999994f);                                     \
  const float NLN2 = sconst(-0.693147180559945f);                            \
  const float C8 = sconst(2.81022636e-08f), C7 = sconst(3.43273939e-07f);    \
  const float C6 = sconst(-3.5233877e-06f), C5 = sconst(-4.39150654e-06f);   \
  const float C4 = sconst(0.00021858087f),  C3 = sconst(-0.00125372503f);    \
  const float C2 = sconst(-0.00417768164f), C1 = sconst(0.246640727f);       \
  const float C0 = sconst(1.50140941f);                                      \
  const float T8 = sconst(-0.000200214257f), T7 = sconst(0.000100950558f);   \
  const float T6 = sconst(0.00134934322f),   T5 = sconst(-0.00367342844f);   \
  const float T4 = sconst(0.00573950773f),   T3 = sconst(-0.0076224613f);    \
  const float T2 = sconst(0.00943887047f),   T1 = sconst(1.00167406f);       \
  const float T0 = sconst(2.83297682f);                                      \
  const float CS = sconst(0.1f * __uint_as_float(0x3FB504F3u));              \
  const float A1 = sconst(1.02f);                                            \
  const float A3 = sconst(-0.02f);

// ---- kernel 2: hot loop, keys via s_load into SGPRs ----
__global__ __launch_bounds__(256, 8) void langevin_sk(
    const float* __restrict__ x0p, const float* __restrict__ bias,
    const int* __restrict__ nsteps_p, const uint4* __restrict__ kw,
    float* __restrict__ out, int N, int ndim) {
  const int n_steps = __builtin_amdgcn_readfirstlane(nsteps_p[0]);
  const int j = (int)(blockIdx.x * blockDim.x + threadIdx.x);
  if (j >= N) return;
  const unsigned cj = (unsigned)j;
  float x = x0p[j];
  const float b = bias[j % ndim];
  DECL_CONSTS
  const float bp = b * -0.01f;  // -DT*b (per-lane)

  const int n4 = (n_steps <= 508) ? (n_steps & ~3) : 0;  // 4-step fast path
  const uint4* kp = kw;
  v4u k0a, k0b, k1a, k1b;
  if (n4 > 0) {  // prologue: steps 0,1 into SGPRs (%2 = pointer!)
    asm volatile("s_load_dwordx4 %0, %2, 0x0\n\t"
                 "s_load_dwordx4 %1, %2, 0x10\n\t"
                 "s_waitcnt lgkmcnt(0)"
                 : "=&s"(k0a), "=&s"(k0b) : "s"(kp));
  }
#pragma unroll 1
  for (int t = 0; t < n4; t += 4) {
    // issue loads for steps t+2,t+3 (consumed this iter, covered by compute)
    asm volatile("s_load_dwordx4 %0, %2, 0x20\n\t"
                 "s_load_dwordx4 %1, %2, 0x30"
                 : "=&s"(k1a), "=&s"(k1b) : "s"(kp));
    unsigned ra, rb;
    tf_fold2k(k0a, k0b, cj, ra, rb);   // steps t, t+1
    NORM2_UPDATE(ra, rb)
    asm volatile("s_waitcnt lgkmcnt(0)" : "+s"(k1a), "+s"(k1b));
    // issue loads for steps t+4,t+5 (next iter; table padded to 512)
    asm volatile("s_load_dwordx4 %0, %2, 0x40\n\t"
                 "s_load_dwordx4 %1, %2, 0x50"
                 : "=&s"(k0a), "=&s"(k0b) : "s"(kp));
    tf_fold2k(k1a, k1b, cj, ra, rb);   // steps t+2, t+3
    NORM2_UPDATE(ra, rb)
    asm volatile("s_waitcnt lgkmcnt(0)" : "+s"(k0a), "+s"(k0b));
    kp += 4;
  }
  // tail / fallback: recompute step keys inline (exact, rarely taken)
  for (int t = n4; t < n_steps; ++t) {
    unsigned o0, o1;
    tf2x32(0u, 1u, 0u, (unsigned)t, o0, o1);
    v4u ka = {o0, o1, o0 ^ o1 ^ 0x1BD11BDAu, 0u};
    unsigned ra, rb;
    tf_fold2k(ka, ka, cj, ra, rb);
    const float fa = __uint_as_float((ra >> 9) | 0x3F800000u) - 1.0f;
    const float ua = fmaf(fa, 2.0f, LO);
    const float wa = __log2f(1.0f - ua * ua) * NLN2;
    float pa, za;
    if (wa < 5.0f) { za = wa - 2.5f;
      pa = C8; pa = fmaf(pa, za, C7); pa = fmaf(pa, za, C6);
      pa = fmaf(pa, za, C5); pa = fmaf(pa, za, C4); pa = fmaf(pa, za, C3);
      pa = fmaf(pa, za, C2); pa = fmaf(pa, za, C1); pa = fmaf(pa, za, C0);
    } else { za = __builtin_amdgcn_sqrtf(wa) - 3.0f;
      pa = T8; pa = fmaf(pa, za, T7); pa = fmaf(pa, za, T6);
      pa = fmaf(pa, za, T5); pa = fmaf(pa, za, T4); pa = fmaf(pa, za, T3);
      pa = fmaf(pa, za, T2); pa = fmaf(pa, za, T1); pa = fmaf(pa, za, T0);
    }
    const float ea = pa * ua;
    const float x3 = (x * x) * x;
    x = fmaf(x, A1, fmaf(x3, A3, fmaf(ea, CS, bp)));
  }
  out[j] = x;
}

extern "C" void kernel_launch(void* const* d_in, const int* in_sizes, int n_in,
                              void* d_out, int out_size, void* d_ws, size_t ws_size,
                              hipStream_t stream) {
  (void)n_in; (void)out_size;
  const float* x0 = (const float*)d_in[0];
  const float* b = (const float*)d_in[1];
  const int* ns = (const int*)d_in[2];
  float* out = (float*)d_out;

  const int n = in_sizes[0];     // 2048*256 = 524288
  const int ndim = in_sizes[1];  // 256
  uint4* kw = (uint4*)d_ws;      // 512 * 16 B = 8 KB key table
  (void)ws_size;                 // harness scratch is >= 8 KB

  hipLaunchKernelGGL(keygen, dim3(2), dim3(256), 0, stream, kw);
  const int block = 256;
  const int grid = (n + block - 1) / block;  // 2048 blocks -> 8/CU
  hipLaunchKernelGGL(langevin_sk, dim3(grid), dim3(block), 0, stream,
                     x0, b, ns, kw, out, n, ndim);
}